// Round 8
// baseline (261.598 us; speedup 1.0000x reference)
//
#include <hip/hip_runtime.h>
#include <hip/hip_bf16.h>
#include <stdint.h>

// Problem constants
#define MPTS  524288      // M per batch
#define NB    2           // N
#define CCH   80          // C
#define HWDIM 64          // H = W
#define HID   64
#define NPTS  (NB * MPTS) // 2^20
#define NCELL 8192        // 2 batches x 16^3

typedef _Float16 f16x2 __attribute__((ext_vector_type(2)));
typedef _Float16 f16x8 __attribute__((ext_vector_type(8)));
typedef float    f32x4 __attribute__((ext_vector_type(4)));

union FragH { uint4 q; f16x8 v; f16x2 h2[4]; _Float16 h[8]; };

// v_fma_mix_f32: acc += (f32)f16(lo/hi of u) * w   — 1 VALU op, no separate cvt.
__device__ __forceinline__ void fma_mix_lo(float& acc, unsigned u, float w) {
    asm volatile("v_fma_mix_f32 %0, %1, %2, %0 op_sel_hi:[1,0,0]"
                 : "+v"(acc) : "v"(u), "v"(w));
}
__device__ __forceinline__ void fma_mix_hi(float& acc, unsigned u, float w) {
    asm volatile("v_fma_mix_f32 %0, %1, %2, %0 op_sel:[1,0,0] op_sel_hi:[1,0,0]"
                 : "+v"(acc) : "v"(u), "v"(w));
}

__device__ __forceinline__ int cell_key(const float* __restrict__ coords, int idx) {
    const float* cp = coords + (size_t)idx * 3;
    int cx = min(max((int)((cp[0] + 1.0f) * 8.0f), 0), 15);
    int cy = min(max((int)((cp[1] + 1.0f) * 8.0f), 0), 15);
    int cz = min(max((int)((cp[2] + 1.0f) * 8.0f), 0), 15);
    return ((idx >> 19) << 12) | (cx << 8) | (cy << 4) | cz;
}

// ---------------------------------------------------------------------------
// Sort K1: histogram points into cells.
__global__ void hist_kernel(const float* __restrict__ coords,
                            unsigned* __restrict__ hist) {
    int idx = blockIdx.x * 256 + threadIdx.x;
    if (idx >= NPTS) return;
    atomicAdd(&hist[cell_key(coords, idx)], 1u);
}

// Sort K2: exclusive scan of 8192 counts -> cursor (in place on same buffer ok,
// single block: all reads complete before writes via barriers).
__global__ __launch_bounds__(1024) void scan_kernel(unsigned* __restrict__ hist) {
    __shared__ unsigned s[1024];
    int t = threadIdx.x;
    unsigned v[8], pre[8], sum = 0;
    #pragma unroll
    for (int j = 0; j < 8; ++j) { v[j] = hist[t * 8 + j]; pre[j] = sum; sum += v[j]; }
    s[t] = sum;
    __syncthreads();
    for (int off = 1; off < 1024; off <<= 1) {
        unsigned x = 0;
        if (t >= off) x = s[t - off];
        __syncthreads();
        if (t >= off) s[t] += x;
        __syncthreads();
    }
    unsigned base = (t > 0) ? s[t - 1] : 0u;
    #pragma unroll
    for (int j = 0; j < 8; ++j) hist[t * 8 + j] = base + pre[j];
}

// Sort K3: scatter point indices into sorted order.
__global__ void scatter_kernel(const float* __restrict__ coords,
                               unsigned* __restrict__ cursor,
                               unsigned* __restrict__ perm) {
    int idx = blockIdx.x * 256 + threadIdx.x;
    if (idx >= NPTS) return;
    unsigned slot = atomicAdd(&cursor[cell_key(coords, idx)], 1u);
    perm[slot] = (unsigned)idx;
}

// ---------------------------------------------------------------------------
// Pre-kernel: planesW[np][y][x][64] fp16 = texel(80ch fp32) @ W1_p(80x64).
__global__ void precompute_planesW(const float* __restrict__ planes,
                                   const float* __restrict__ W1,
                                   unsigned short* __restrict__ planesW) {
    __shared__ float tA[CCH * 64];   // [c][px]
    __shared__ float tW[CCH * 64];   // [c][nn]
    int b  = blockIdx.x;
    int np = b >> 6, y = b & 63;
    int p  = np % 3;
    int t  = threadIdx.x;
    for (int i = t; i < CCH * 64; i += 256) {
        int c = i >> 6, x = i & 63;
        tA[i] = planes[((size_t)np * CCH + c) * 4096 + y * 64 + x];
        tW[i] = W1[(p * CCH + c) * HID + x];
    }
    __syncthreads();
    int px = t >> 2;
    int n0 = (t & 3) * 16;
    float acc[16];
    #pragma unroll
    for (int i = 0; i < 16; ++i) acc[i] = 0.0f;
    for (int c = 0; c < CCH; ++c) {
        float a = tA[c * 64 + px];
        #pragma unroll
        for (int i = 0; i < 16; ++i) acc[i] += a * tW[c * 64 + n0 + i];
    }
    unsigned short* dst = planesW + (((size_t)np * 4096) + y * 64 + px) * HID + n0;
    #pragma unroll
    for (int i = 0; i < 16; ++i) {
        union { _Float16 h; unsigned short u; } cv;
        cv.h = (_Float16)acc[i];
        dst[i] = cv.u;
    }
}

// ---------------------------------------------------------------------------
// Pre-kernel: W2, W3 (64x64) fp16 MFMA B-fragment order (proven layout).
__global__ void pack_weights23(const float* __restrict__ W2,
                               const float* __restrict__ W3,
                               unsigned short* __restrict__ wpack) {
    int e = blockIdx.x * 256 + threadIdx.x;   // 0..8191
    const float* W = (e < 4096) ? W2 : W3;
    int q  = e & 4095;
    int j  = q & 7;
    int l  = (q >> 3) & 63;
    int nt = (q >> 9) & 3;
    int kb = q >> 11;
    int k  = kb * 32 + ((l >> 4) << 3) + j;
    int nn = nt * 16 + (l & 15);
    union { _Float16 h; unsigned short u; } cv;
    cv.h = (_Float16)W[k * HID + nn];
    wpack[e] = cv.u;
}

// ---------------------------------------------------------------------------
// Main fused kernel: 256 threads = 4 waves, 64 sorted points per block.
__global__ __launch_bounds__(256, 4) void fused_kernel(
        const unsigned short* __restrict__ planesW,
        const float* __restrict__ coords,
        const unsigned* __restrict__ perm,
        const unsigned short* __restrict__ wpack,
        const float* __restrict__ b1, const float* __restrict__ b2,
        const float* __restrict__ b3, const float* __restrict__ W4,
        const float* __restrict__ b4, float* __restrict__ out) {

    __shared__ __align__(16) unsigned short sH[4 * 16 * 72]; // per-wave H tiles
    __shared__ __align__(16) uint4 sSet[64][3][2];           // {off4, wgt4} per (pt, plane)
    __shared__ unsigned sPermL[64];                          // global point idx per slot

    int t    = threadIdx.x;
    int wave = t >> 6, lane = t & 63;

    unsigned short* hw = sH + wave * (16 * 72);
    _Float16* hwh = (_Float16*)hw;

    // ---------- Sub-phase A: per-point bilinear setup (sorted indirection) --
    if (t < 192) {
        int i  = t & 63;                     // local slot
        int p  = t >> 6;                     // plane (wave-uniform)
        unsigned mypt = perm[blockIdx.x * 64 + i];
        if (t < 64) sPermL[i] = mypt;
        int n = (int)(mypt >> 19);           // MPTS = 2^19
        const float* cp = coords + (size_t)mypt * 3;
        float c0 = cp[0], c1 = cp[1], c2 = cp[2];
        float gx = (p == 2) ? c2 : c0;       // p0:(x,y) p1:(x,z) p2:(z,y)
        float gy = (p == 1) ? c2 : c1;
        float fx = (gx + 1.0f) * 32.0f - 0.5f;
        float fy = (gy + 1.0f) * 32.0f - 0.5f;
        float xf = floorf(fx), yf = floorf(fy);
        float wx = fx - xf,    wy = fy - yf;
        int x0 = (int)xf, y0 = (int)yf, x1 = x0 + 1, y1 = y0 + 1;
        float vx0 = (x0 >= 0 && x0 < 64) ? 1.0f : 0.0f;
        float vx1 = (x1 >= 0 && x1 < 64) ? 1.0f : 0.0f;
        float vy0 = (y0 >= 0 && y0 < 64) ? 1.0f : 0.0f;
        float vy1 = (y1 >= 0 && y1 < 64) ? 1.0f : 0.0f;
        int cx0 = min(max(x0, 0), 63), cx1 = min(max(x1, 0), 63);
        int cy0 = min(max(y0, 0), 63), cy1 = min(max(y1, 0), 63);
        union { float f[4]; uint4 q; } wq;
        wq.f[0] = (1.0f - wx) * (1.0f - wy) * vx0 * vy0;
        wq.f[1] = wx * (1.0f - wy) * vx1 * vy0;
        wq.f[2] = (1.0f - wx) * wy * vx0 * vy1;
        wq.f[3] = wx * wy * vx1 * vy1;
        int base = (n * 3 + p) * 4096;
        uint4 oq;
        oq.x = (unsigned)((base + (cy0 << 6) + cx0) * HID);
        oq.y = (unsigned)((base + (cy0 << 6) + cx1) * HID);
        oq.z = (unsigned)((base + (cy1 << 6) + cx0) * HID);
        oq.w = (unsigned)((base + (cy1 << 6) + cx1) * HID);
        sSet[i][p][0] = oq;
        sSet[i][p][1] = wq.q;
    }
    __syncthreads();

    // ---------- Sub-phase B: gather + layer-1 accumulate -------------------
    {
        int sub = lane & 7;                  // 8-dim octet
        int ptg = lane >> 3;                 // point group

        float b1f0, b1f1, b1f2, b1f3, b1f4, b1f5, b1f6, b1f7;
        {
            const float4* bp = (const float4*)(b1 + sub * 8);
            float4 v0 = bp[0], v1 = bp[1];
            b1f0 = v0.x; b1f1 = v0.y; b1f2 = v0.z; b1f3 = v0.w;
            b1f4 = v1.x; b1f5 = v1.y; b1f6 = v1.z; b1f7 = v1.w;
        }
        const unsigned short* pw = planesW + sub * 8;

        auto do_round = [&](int pt) {
            int pl = wave * 16 + pt;
            uint4 o0 = sSet[pl][0][0], w0c = sSet[pl][0][1];
            uint4 o1 = sSet[pl][1][0], w1c = sSet[pl][1][1];
            uint4 o2 = sSet[pl][2][0], w2c = sSet[pl][2][1];

            FragH u0, u1, u2, u3, u4, u5, u6, u7, u8, u9, u10, u11;
            u0.q  = *(const uint4*)(pw + o0.x);
            u1.q  = *(const uint4*)(pw + o0.y);
            u2.q  = *(const uint4*)(pw + o0.z);
            u3.q  = *(const uint4*)(pw + o0.w);
            u4.q  = *(const uint4*)(pw + o1.x);
            u5.q  = *(const uint4*)(pw + o1.y);
            u6.q  = *(const uint4*)(pw + o1.z);
            u7.q  = *(const uint4*)(pw + o1.w);
            u8.q  = *(const uint4*)(pw + o2.x);
            u9.q  = *(const uint4*)(pw + o2.y);
            u10.q = *(const uint4*)(pw + o2.z);
            u11.q = *(const uint4*)(pw + o2.w);

            float a0 = b1f0, a1 = b1f1, a2 = b1f2, a3 = b1f3;
            float a4 = b1f4, a5 = b1f5, a6 = b1f6, a7 = b1f7;
            union { unsigned u; float f; } cvu;

            #define TEXEL(T, WB) { cvu.u = (WB); float w = cvu.f;            \
                fma_mix_lo(a0, T.q.x, w); fma_mix_hi(a1, T.q.x, w);          \
                fma_mix_lo(a2, T.q.y, w); fma_mix_hi(a3, T.q.y, w);          \
                fma_mix_lo(a4, T.q.z, w); fma_mix_hi(a5, T.q.z, w);          \
                fma_mix_lo(a6, T.q.w, w); fma_mix_hi(a7, T.q.w, w); }
            TEXEL(u0,  w0c.x) TEXEL(u1,  w0c.y) TEXEL(u2,  w0c.z) TEXEL(u3,  w0c.w)
            TEXEL(u4,  w1c.x) TEXEL(u5,  w1c.y) TEXEL(u6,  w1c.z) TEXEL(u7,  w1c.w)
            TEXEL(u8,  w2c.x) TEXEL(u9,  w2c.y) TEXEL(u10, w2c.z) TEXEL(u11, w2c.w)
            #undef TEXEL

            FragH hv;
            hv.h[0] = (_Float16)fmaxf(a0, 0.0f);
            hv.h[1] = (_Float16)fmaxf(a1, 0.0f);
            hv.h[2] = (_Float16)fmaxf(a2, 0.0f);
            hv.h[3] = (_Float16)fmaxf(a3, 0.0f);
            hv.h[4] = (_Float16)fmaxf(a4, 0.0f);
            hv.h[5] = (_Float16)fmaxf(a5, 0.0f);
            hv.h[6] = (_Float16)fmaxf(a6, 0.0f);
            hv.h[7] = (_Float16)fmaxf(a7, 0.0f);
            *(uint4*)(hwh + pt * 72 + sub * 8) = hv.q;
        };
        do_round(ptg);
        do_round(8 + ptg);
    }
    __syncthreads();

    // ---------- Layer 2: K=64, A from LDS, B from global (proven) ----------
    int row  = lane & 15;
    int kgrp = lane >> 4;
    f32x4 acc2[4] = {{0,0,0,0},{0,0,0,0},{0,0,0,0},{0,0,0,0}};
    #pragma unroll
    for (int kk = 0; kk < 2; ++kk) {
        FragH au;
        au.q = *(const uint4*)(hw + row * 72 + kk * 32 + kgrp * 8);
        #pragma unroll
        for (int nt = 0; nt < 4; ++nt) {
            FragH bu;
            bu.q = *(const uint4*)(wpack + (kk * 4 + nt) * 512 + lane * 8);
            acc2[nt] = __builtin_amdgcn_mfma_f32_16x16x32_f16(au.v, bu.v, acc2[nt], 0, 0, 0);
        }
    }
    __syncthreads();

    // Epilogue 2
    #pragma unroll
    for (int nt = 0; nt < 4; ++nt) {
        float bb = b2[nt * 16 + row];
        #pragma unroll
        for (int r = 0; r < 4; ++r) {
            float h = fmaxf(acc2[nt][r] + bb, 0.0f);
            hwh[(kgrp * 4 + r) * 72 + nt * 16 + row] = (_Float16)h;
        }
    }
    __syncthreads();

    // ---------- Layer 3: K=64, B from global --------------------------------
    f32x4 acc3[4] = {{0,0,0,0},{0,0,0,0},{0,0,0,0},{0,0,0,0}};
    #pragma unroll
    for (int kk = 0; kk < 2; ++kk) {
        FragH au;
        au.q = *(const uint4*)(hw + row * 72 + kk * 32 + kgrp * 8);
        #pragma unroll
        for (int nt = 0; nt < 4; ++nt) {
            FragH bu;
            bu.q = *(const uint4*)(wpack + 4096 + (kk * 4 + nt) * 512 + lane * 8);
            acc3[nt] = __builtin_amdgcn_mfma_f32_16x16x32_f16(au.v, bu.v, acc3[nt], 0, 0, 0);
        }
    }

    // ---------- Layer 4: 64 -> 1, fp32 VALU + 16-lane reduce ----------------
    float part[4] = {0.f, 0.f, 0.f, 0.f};
    #pragma unroll
    for (int nt = 0; nt < 4; ++nt) {
        float bb  = b3[nt * 16 + row];
        float w4v = W4[nt * 16 + row];
        #pragma unroll
        for (int r = 0; r < 4; ++r) {
            float h = fmaxf(acc3[nt][r] + bb, 0.0f);
            part[r] += h * w4v;
        }
    }
    #pragma unroll
    for (int r = 0; r < 4; ++r) {
        #pragma unroll
        for (int off = 1; off < 16; off <<= 1)
            part[r] += __shfl_xor(part[r], off);
    }
    if (row == 0) {
        float bias4 = b4[0];
        #pragma unroll
        for (int r = 0; r < 4; ++r)
            out[sPermL[wave * 16 + kgrp * 4 + r]] = part[r] + bias4;
    }
}

// ---------------------------------------------------------------------------
extern "C" void kernel_launch(void* const* d_in, const int* in_sizes, int n_in,
                              void* d_out, int out_size, void* d_ws, size_t ws_size,
                              hipStream_t stream) {
    const float* planes = (const float*)d_in[0];
    const float* coords = (const float*)d_in[1];
    const float* W1 = (const float*)d_in[2];
    const float* b1 = (const float*)d_in[3];
    const float* W2 = (const float*)d_in[4];
    const float* b2 = (const float*)d_in[5];
    const float* W3 = (const float*)d_in[6];
    const float* b3 = (const float*)d_in[7];
    const float* W4 = (const float*)d_in[8];
    const float* b4 = (const float*)d_in[9];
    float* out = (float*)d_out;

    // Workspace layout:
    //   planesW fp16 : [0, 3145728)
    //   wpack fp16   : [3145728, 3162112)
    //   cursor u32   : [3162112, 3194880)   (8192 * 4)
    //   perm u32     : [3194880, 7389184)   (2^20 * 4)
    unsigned short* planesW = (unsigned short*)d_ws;
    unsigned short* wpack   = (unsigned short*)((char*)d_ws + 3145728);
    unsigned*       cursor  = (unsigned*)((char*)d_ws + 3162112);
    unsigned*       perm    = (unsigned*)((char*)d_ws + 3194880);

    hipMemsetAsync(cursor, 0, NCELL * sizeof(unsigned), stream);
    hipLaunchKernelGGL(hist_kernel, dim3(NPTS / 256), dim3(256), 0, stream,
                       coords, cursor);
    hipLaunchKernelGGL(scan_kernel, dim3(1), dim3(1024), 0, stream, cursor);
    hipLaunchKernelGGL(scatter_kernel, dim3(NPTS / 256), dim3(256), 0, stream,
                       coords, cursor, perm);

    hipLaunchKernelGGL(precompute_planesW, dim3(NB * 3 * HWDIM), dim3(256), 0, stream,
                       planes, W1, planesW);
    hipLaunchKernelGGL(pack_weights23, dim3(32), dim3(256), 0, stream,
                       W2, W3, wpack);

    int nblocks = NPTS / 64;   // 16384
    hipLaunchKernelGGL(fused_kernel, dim3(nblocks), dim3(256), 0, stream,
                       planesW, coords, perm, wpack, b1, b2, b3, W4, b4, out);
}

// Round 10
// 101.968 us; speedup vs baseline: 2.5655x; 2.5655x over previous
//
#include <hip/hip_runtime.h>
#include <hip/hip_bf16.h>
#include <stdint.h>

// Problem constants
#define MPTS  524288      // M per batch
#define NB    2           // N
#define CCH   80          // C
#define HWDIM 64          // H = W
#define HID   64
#define NPTS  (NB * MPTS) // 2^20

typedef _Float16 f16x2 __attribute__((ext_vector_type(2)));
typedef _Float16 f16x8 __attribute__((ext_vector_type(8)));
typedef float    f32x4 __attribute__((ext_vector_type(4)));

union FragH { uint4 q; f16x8 v; f16x2 h2[4]; _Float16 h[8]; };

// v_fma_mix_f32: acc += (f32)f16(lo/hi of u) * w   — 1 VALU op, no separate cvt.
__device__ __forceinline__ void fma_mix_lo(float& acc, unsigned u, float w) {
    asm volatile("v_fma_mix_f32 %0, %1, %2, %0 op_sel_hi:[1,0,0]"
                 : "+v"(acc) : "v"(u), "v"(w));
}
__device__ __forceinline__ void fma_mix_hi(float& acc, unsigned u, float w) {
    asm volatile("v_fma_mix_f32 %0, %1, %2, %0 op_sel:[1,0,0] op_sel_hi:[1,0,0]"
                 : "+v"(acc) : "v"(u), "v"(w));
}

// ---------------------------------------------------------------------------
// Pre-kernel: planesW[np][y][x][64] fp16 = texel(80ch fp32) @ W1_p(80x64).
__global__ void precompute_planesW(const float* __restrict__ planes,
                                   const float* __restrict__ W1,
                                   unsigned short* __restrict__ planesW) {
    __shared__ float tA[CCH * 64];   // [c][px]
    __shared__ float tW[CCH * 64];   // [c][nn]
    int b  = blockIdx.x;
    int np = b >> 6, y = b & 63;
    int p  = np % 3;
    int t  = threadIdx.x;
    for (int i = t; i < CCH * 64; i += 256) {
        int c = i >> 6, x = i & 63;
        tA[i] = planes[((size_t)np * CCH + c) * 4096 + y * 64 + x];
        tW[i] = W1[(p * CCH + c) * HID + x];
    }
    __syncthreads();
    int px = t >> 2;
    int n0 = (t & 3) * 16;
    float acc[16];
    #pragma unroll
    for (int i = 0; i < 16; ++i) acc[i] = 0.0f;
    for (int c = 0; c < CCH; ++c) {
        float a = tA[c * 64 + px];
        #pragma unroll
        for (int i = 0; i < 16; ++i) acc[i] += a * tW[c * 64 + n0 + i];
    }
    unsigned short* dst = planesW + (((size_t)np * 4096) + y * 64 + px) * HID + n0;
    #pragma unroll
    for (int i = 0; i < 16; ++i) {
        union { _Float16 h; unsigned short u; } cv;
        cv.h = (_Float16)acc[i];
        dst[i] = cv.u;
    }
}

// ---------------------------------------------------------------------------
// Pre-kernel: W2, W3 (64x64) fp16 MFMA B-fragment order (proven layout).
__global__ void pack_weights23(const float* __restrict__ W2,
                               const float* __restrict__ W3,
                               unsigned short* __restrict__ wpack) {
    int e = blockIdx.x * 256 + threadIdx.x;   // 0..8191
    const float* W = (e < 4096) ? W2 : W3;
    int q  = e & 4095;
    int j  = q & 7;
    int l  = (q >> 3) & 63;
    int nt = (q >> 9) & 3;
    int kb = q >> 11;
    int k  = kb * 32 + ((l >> 4) << 3) + j;
    int nn = nt * 16 + (l & 15);
    union { _Float16 h; unsigned short u; } cv;
    cv.h = (_Float16)W[k * HID + nn];
    wpack[e] = cv.u;
}

// ---------------------------------------------------------------------------
// Main fused kernel: 256 threads = 4 waves, 64 points per block.
// W2/W3 fragments + biases staged in LDS: removes ~256 TA line-cycles/wave.
__global__ __launch_bounds__(256, 4) void fused_kernel(
        const unsigned short* __restrict__ planesW,
        const float* __restrict__ coords,
        const unsigned short* __restrict__ wpack,
        const float* __restrict__ b1, const float* __restrict__ b2,
        const float* __restrict__ b3, const float* __restrict__ W4,
        const float* __restrict__ b4, float* __restrict__ out) {

    __shared__ __align__(16) unsigned short sH[4 * 16 * 72]; // per-wave H tiles
    __shared__ __align__(16) uint4 sSet[64][3][2];           // {off4, wgt4} per (pt, plane)
    __shared__ __align__(16) unsigned short sW23[8192];      // W2|W3 fragments (16 KB = 1024 uint4)
    __shared__ float sBias[196];                             // b2[0:64) b3[64:128) W4[128:192) b4[192]

    int t    = threadIdx.x;
    int wave = t >> 6, lane = t & 63;
    int ptbase = blockIdx.x * 64 + wave * 16;

    unsigned short* hw = sH + wave * (16 * 72);
    _Float16* hwh = (_Float16*)hw;

    // ---------- Stage W2/W3 fragments + biases into LDS --------------------
    // sW23 = 1024 uint4; 256 threads x 4 chunks.  (Round-9 bug: only 2 chunks.)
    {
        const uint4* g = (const uint4*)wpack;
        uint4* s = (uint4*)sW23;
        s[t]       = g[t];
        s[t + 256] = g[t + 256];
        s[t + 512] = g[t + 512];
        s[t + 768] = g[t + 768];
        if (t < 64)        sBias[t] = b2[t];
        else if (t < 128)  sBias[t] = b3[t - 64];
        else if (t < 192)  sBias[t] = W4[t - 128];
        else if (t == 192) sBias[192] = b4[0];
    }

    // ---------- Sub-phase A: per-point bilinear setup, deduplicated --------
    if (t < 192) {
        int i  = t & 63;                     // local point
        int p  = t >> 6;                     // plane (wave-uniform)
        int mypt = blockIdx.x * 64 + i;
        int n    = mypt >> 19;               // MPTS = 2^19
        const float* cp = coords + (size_t)mypt * 3;
        float c0 = cp[0], c1 = cp[1], c2 = cp[2];
        float gx = (p == 2) ? c2 : c0;       // p0:(x,y) p1:(x,z) p2:(z,y)
        float gy = (p == 1) ? c2 : c1;
        float fx = (gx + 1.0f) * 32.0f - 0.5f;
        float fy = (gy + 1.0f) * 32.0f - 0.5f;
        float xf = floorf(fx), yf = floorf(fy);
        float wx = fx - xf,    wy = fy - yf;
        int x0 = (int)xf, y0 = (int)yf, x1 = x0 + 1, y1 = y0 + 1;
        float vx0 = (x0 >= 0 && x0 < 64) ? 1.0f : 0.0f;
        float vx1 = (x1 >= 0 && x1 < 64) ? 1.0f : 0.0f;
        float vy0 = (y0 >= 0 && y0 < 64) ? 1.0f : 0.0f;
        float vy1 = (y1 >= 0 && y1 < 64) ? 1.0f : 0.0f;
        int cx0 = min(max(x0, 0), 63), cx1 = min(max(x1, 0), 63);
        int cy0 = min(max(y0, 0), 63), cy1 = min(max(y1, 0), 63);
        union { float f[4]; uint4 q; } wq;
        wq.f[0] = (1.0f - wx) * (1.0f - wy) * vx0 * vy0;
        wq.f[1] = wx * (1.0f - wy) * vx1 * vy0;
        wq.f[2] = (1.0f - wx) * wy * vx0 * vy1;
        wq.f[3] = wx * wy * vx1 * vy1;
        int base = (n * 3 + p) * 4096;
        uint4 oq;
        oq.x = (unsigned)((base + (cy0 << 6) + cx0) * HID);
        oq.y = (unsigned)((base + (cy0 << 6) + cx1) * HID);
        oq.z = (unsigned)((base + (cy1 << 6) + cx0) * HID);
        oq.w = (unsigned)((base + (cy1 << 6) + cx1) * HID);
        sSet[i][p][0] = oq;
        sSet[i][p][1] = wq.q;
    }
    __syncthreads();

    // ---------- Sub-phase B: gather + layer-1 accumulate -------------------
    {
        int sub = lane & 7;                  // 8-dim octet
        int ptg = lane >> 3;                 // point group

        float b1f0, b1f1, b1f2, b1f3, b1f4, b1f5, b1f6, b1f7;
        {
            const float4* bp = (const float4*)(b1 + sub * 8);
            float4 v0 = bp[0], v1 = bp[1];
            b1f0 = v0.x; b1f1 = v0.y; b1f2 = v0.z; b1f3 = v0.w;
            b1f4 = v1.x; b1f5 = v1.y; b1f6 = v1.z; b1f7 = v1.w;
        }
        const unsigned short* pw = planesW + sub * 8;

        auto do_round = [&](int pt) {
            int pl = wave * 16 + pt;
            uint4 o0 = sSet[pl][0][0], w0c = sSet[pl][0][1];
            uint4 o1 = sSet[pl][1][0], w1c = sSet[pl][1][1];
            uint4 o2 = sSet[pl][2][0], w2c = sSet[pl][2][1];

            FragH u0, u1, u2, u3, u4, u5, u6, u7, u8, u9, u10, u11;
            u0.q  = *(const uint4*)(pw + o0.x);
            u1.q  = *(const uint4*)(pw + o0.y);
            u2.q  = *(const uint4*)(pw + o0.z);
            u3.q  = *(const uint4*)(pw + o0.w);
            u4.q  = *(const uint4*)(pw + o1.x);
            u5.q  = *(const uint4*)(pw + o1.y);
            u6.q  = *(const uint4*)(pw + o1.z);
            u7.q  = *(const uint4*)(pw + o1.w);
            u8.q  = *(const uint4*)(pw + o2.x);
            u9.q  = *(const uint4*)(pw + o2.y);
            u10.q = *(const uint4*)(pw + o2.z);
            u11.q = *(const uint4*)(pw + o2.w);

            float a0 = b1f0, a1 = b1f1, a2 = b1f2, a3 = b1f3;
            float a4 = b1f4, a5 = b1f5, a6 = b1f6, a7 = b1f7;
            union { unsigned u; float f; } cvu;

            #define TEXEL(T, WB) { cvu.u = (WB); float w = cvu.f;            \
                fma_mix_lo(a0, T.q.x, w); fma_mix_hi(a1, T.q.x, w);          \
                fma_mix_lo(a2, T.q.y, w); fma_mix_hi(a3, T.q.y, w);          \
                fma_mix_lo(a4, T.q.z, w); fma_mix_hi(a5, T.q.z, w);          \
                fma_mix_lo(a6, T.q.w, w); fma_mix_hi(a7, T.q.w, w); }
            TEXEL(u0,  w0c.x) TEXEL(u1,  w0c.y) TEXEL(u2,  w0c.z) TEXEL(u3,  w0c.w)
            TEXEL(u4,  w1c.x) TEXEL(u5,  w1c.y) TEXEL(u6,  w1c.z) TEXEL(u7,  w1c.w)
            TEXEL(u8,  w2c.x) TEXEL(u9,  w2c.y) TEXEL(u10, w2c.z) TEXEL(u11, w2c.w)
            #undef TEXEL

            FragH hv;
            hv.h[0] = (_Float16)fmaxf(a0, 0.0f);
            hv.h[1] = (_Float16)fmaxf(a1, 0.0f);
            hv.h[2] = (_Float16)fmaxf(a2, 0.0f);
            hv.h[3] = (_Float16)fmaxf(a3, 0.0f);
            hv.h[4] = (_Float16)fmaxf(a4, 0.0f);
            hv.h[5] = (_Float16)fmaxf(a5, 0.0f);
            hv.h[6] = (_Float16)fmaxf(a6, 0.0f);
            hv.h[7] = (_Float16)fmaxf(a7, 0.0f);
            *(uint4*)(hwh + pt * 72 + sub * 8) = hv.q;
        };
        do_round(ptg);
        do_round(8 + ptg);
    }
    __syncthreads();

    // ---------- Layer 2: K=64, A from LDS, B from LDS ----------------------
    int row  = lane & 15;
    int kgrp = lane >> 4;
    f32x4 acc2[4] = {{0,0,0,0},{0,0,0,0},{0,0,0,0},{0,0,0,0}};
    #pragma unroll
    for (int kk = 0; kk < 2; ++kk) {
        FragH au;
        au.q = *(const uint4*)(hw + row * 72 + kk * 32 + kgrp * 8);
        #pragma unroll
        for (int nt = 0; nt < 4; ++nt) {
            FragH bu;
            bu.q = *(const uint4*)(sW23 + (kk * 4 + nt) * 512 + lane * 8);
            acc2[nt] = __builtin_amdgcn_mfma_f32_16x16x32_f16(au.v, bu.v, acc2[nt], 0, 0, 0);
        }
    }
    __syncthreads();

    // Epilogue 2 (biases from LDS)
    #pragma unroll
    for (int nt = 0; nt < 4; ++nt) {
        float bb = sBias[nt * 16 + row];
        #pragma unroll
        for (int r = 0; r < 4; ++r) {
            float h = fmaxf(acc2[nt][r] + bb, 0.0f);
            hwh[(kgrp * 4 + r) * 72 + nt * 16 + row] = (_Float16)h;
        }
    }
    __syncthreads();

    // ---------- Layer 3: K=64, B from LDS -----------------------------------
    f32x4 acc3[4] = {{0,0,0,0},{0,0,0,0},{0,0,0,0},{0,0,0,0}};
    #pragma unroll
    for (int kk = 0; kk < 2; ++kk) {
        FragH au;
        au.q = *(const uint4*)(hw + row * 72 + kk * 32 + kgrp * 8);
        #pragma unroll
        for (int nt = 0; nt < 4; ++nt) {
            FragH bu;
            bu.q = *(const uint4*)(sW23 + 4096 + (kk * 4 + nt) * 512 + lane * 8);
            acc3[nt] = __builtin_amdgcn_mfma_f32_16x16x32_f16(au.v, bu.v, acc3[nt], 0, 0, 0);
        }
    }

    // ---------- Layer 4: 64 -> 1, fp32 VALU + 16-lane reduce ----------------
    float part[4] = {0.f, 0.f, 0.f, 0.f};
    #pragma unroll
    for (int nt = 0; nt < 4; ++nt) {
        float bb  = sBias[64 + nt * 16 + row];
        float w4v = sBias[128 + nt * 16 + row];
        #pragma unroll
        for (int r = 0; r < 4; ++r) {
            float h = fmaxf(acc3[nt][r] + bb, 0.0f);
            part[r] += h * w4v;
        }
    }
    #pragma unroll
    for (int r = 0; r < 4; ++r) {
        #pragma unroll
        for (int off = 1; off < 16; off <<= 1)
            part[r] += __shfl_xor(part[r], off);
    }
    if (row == 0) {
        float bias4 = sBias[192];
        float4 o;
        o.x = part[0] + bias4; o.y = part[1] + bias4;
        o.z = part[2] + bias4; o.w = part[3] + bias4;
        *(float4*)(out + ptbase + kgrp * 4) = o;
    }
}

// ---------------------------------------------------------------------------
extern "C" void kernel_launch(void* const* d_in, const int* in_sizes, int n_in,
                              void* d_out, int out_size, void* d_ws, size_t ws_size,
                              hipStream_t stream) {
    const float* planes = (const float*)d_in[0];
    const float* coords = (const float*)d_in[1];
    const float* W1 = (const float*)d_in[2];
    const float* b1 = (const float*)d_in[3];
    const float* W2 = (const float*)d_in[4];
    const float* b2 = (const float*)d_in[5];
    const float* W3 = (const float*)d_in[6];
    const float* b3 = (const float*)d_in[7];
    const float* W4 = (const float*)d_in[8];
    const float* b4 = (const float*)d_in[9];
    float* out = (float*)d_out;

    // Workspace: planesW fp16 (3,145,728 B) | wpack fp16 (16,384 B)
    unsigned short* planesW = (unsigned short*)d_ws;
    unsigned short* wpack   = (unsigned short*)((char*)d_ws + 3145728);

    hipLaunchKernelGGL(precompute_planesW, dim3(NB * 3 * HWDIM), dim3(256), 0, stream,
                       planes, W1, planesW);
    hipLaunchKernelGGL(pack_weights23, dim3(32), dim3(256), 0, stream,
                       W2, W3, wpack);

    int nblocks = NPTS / 64;   // 16384
    hipLaunchKernelGGL(fused_kernel, dim3(nblocks), dim3(256), 0, stream,
                       planesW, coords, wpack, b1, b2, b3, W4, b4, out);
}

// Round 11
// 96.616 us; speedup vs baseline: 2.7076x; 1.0554x over previous
//
#include <hip/hip_runtime.h>
#include <hip/hip_bf16.h>
#include <stdint.h>

// Problem constants
#define MPTS  524288      // M per batch
#define NB    2           // N
#define CCH   80          // C
#define HWDIM 64          // H = W
#define HID   64
#define NPTS  (NB * MPTS) // 2^20

typedef _Float16 f16x2 __attribute__((ext_vector_type(2)));
typedef _Float16 f16x8 __attribute__((ext_vector_type(8)));
typedef float    f32x4 __attribute__((ext_vector_type(4)));

union FragH { uint4 q; f16x8 v; f16x2 h2[4]; unsigned d[4]; _Float16 h[8]; };
union PkU   { f16x2 v; unsigned u; };

// v_pk_fma_f16: acc.lo += a.lo*b.lo ; acc.hi += a.hi*b.hi  (1 VALU op, 2 MACs)
__device__ __forceinline__ void pk_fma(unsigned& acc, unsigned a, unsigned b) {
    asm volatile("v_pk_fma_f16 %0, %1, %2, %0" : "+v"(acc) : "v"(a), "v"(b));
}
__device__ __forceinline__ unsigned pk_relu(unsigned a) {
    unsigned r;
    asm volatile("v_pk_max_f16 %0, %1, %2" : "=v"(r) : "v"(a), "v"(0u));
    return r;
}

// ---------------------------------------------------------------------------
// Pre-kernel: planesW[np][y][x][64] fp16 = texel(80ch fp32) @ W1_p(80x64).
__global__ void precompute_planesW(const float* __restrict__ planes,
                                   const float* __restrict__ W1,
                                   unsigned short* __restrict__ planesW) {
    __shared__ float tA[CCH * 64];   // [c][px]
    __shared__ float tW[CCH * 64];   // [c][nn]
    int b  = blockIdx.x;
    int np = b >> 6, y = b & 63;
    int p  = np % 3;
    int t  = threadIdx.x;
    for (int i = t; i < CCH * 64; i += 256) {
        int c = i >> 6, x = i & 63;
        tA[i] = planes[((size_t)np * CCH + c) * 4096 + y * 64 + x];
        tW[i] = W1[(p * CCH + c) * HID + x];
    }
    __syncthreads();
    int px = t >> 2;
    int n0 = (t & 3) * 16;
    float acc[16];
    #pragma unroll
    for (int i = 0; i < 16; ++i) acc[i] = 0.0f;
    for (int c = 0; c < CCH; ++c) {
        float a = tA[c * 64 + px];
        #pragma unroll
        for (int i = 0; i < 16; ++i) acc[i] += a * tW[c * 64 + n0 + i];
    }
    unsigned short* dst = planesW + (((size_t)np * 4096) + y * 64 + px) * HID + n0;
    #pragma unroll
    for (int i = 0; i < 16; ++i) {
        union { _Float16 h; unsigned short u; } cv;
        cv.h = (_Float16)acc[i];
        dst[i] = cv.u;
    }
}

// ---------------------------------------------------------------------------
// Pre-kernel: W2, W3 (64x64) fp16 MFMA B-fragment order (proven layout).
__global__ void pack_weights23(const float* __restrict__ W2,
                               const float* __restrict__ W3,
                               unsigned short* __restrict__ wpack) {
    int e = blockIdx.x * 256 + threadIdx.x;   // 0..8191
    const float* W = (e < 4096) ? W2 : W3;
    int q  = e & 4095;
    int j  = q & 7;
    int l  = (q >> 3) & 63;
    int nt = (q >> 9) & 3;
    int kb = q >> 11;
    int k  = kb * 32 + ((l >> 4) << 3) + j;
    int nn = nt * 16 + (l & 15);
    union { _Float16 h; unsigned short u; } cv;
    cv.h = (_Float16)W[k * HID + nn];
    wpack[e] = cv.u;
}

// ---------------------------------------------------------------------------
// Main fused kernel: 256 threads = 4 waves, 64 points per block.
// Single block-wide barrier (after staging + setup); all later phases are
// wave-private (H tiles) or read-only LDS -> waves slide independently.
__global__ __launch_bounds__(256, 4) void fused_kernel(
        const unsigned short* __restrict__ planesW,
        const float* __restrict__ coords,
        const unsigned short* __restrict__ wpack,
        const float* __restrict__ b1, const float* __restrict__ b2,
        const float* __restrict__ b3, const float* __restrict__ W4,
        const float* __restrict__ b4, float* __restrict__ out) {

    __shared__ __align__(16) unsigned short sH[4 * 16 * 72]; // per-wave H tiles
    __shared__ __align__(16) uint4 sSet[64][3][2];           // {off4(elem), wpk4(f16 splat)} per (pt, plane)
    __shared__ __align__(16) unsigned short sW23[8192];      // W2|W3 fragments (16 KB = 1024 uint4)
    __shared__ float sBias[196];                             // b2[0:64) b3[64:128) W4[128:192) b4[192]

    int t    = threadIdx.x;
    int wave = t >> 6, lane = t & 63;
    int ptbase = blockIdx.x * 64 + wave * 16;

    unsigned short* hw = sH + wave * (16 * 72);
    _Float16* hwh = (_Float16*)hw;

    // ---------- Stage W2/W3 fragments + biases into LDS --------------------
    {
        const uint4* g = (const uint4*)wpack;
        uint4* s = (uint4*)sW23;
        s[t]       = g[t];
        s[t + 256] = g[t + 256];
        s[t + 512] = g[t + 512];
        s[t + 768] = g[t + 768];
        if (t < 64)        sBias[t] = b2[t];
        else if (t < 128)  sBias[t] = b3[t - 64];
        else if (t < 192)  sBias[t] = W4[t - 128];
        else if (t == 192) sBias[192] = b4[0];
    }

    // ---------- Sub-phase A: per-point bilinear setup, deduplicated --------
    // Weights stored as packed fp16 splat pairs (ready for v_pk_fma_f16).
    if (t < 192) {
        int i  = t & 63;                     // local point
        int p  = t >> 6;                     // plane (wave-uniform)
        int mypt = blockIdx.x * 64 + i;
        int n    = mypt >> 19;               // MPTS = 2^19
        const float* cp = coords + (size_t)mypt * 3;
        float c0 = cp[0], c1 = cp[1], c2 = cp[2];
        float gx = (p == 2) ? c2 : c0;       // p0:(x,y) p1:(x,z) p2:(z,y)
        float gy = (p == 1) ? c2 : c1;
        float fx = (gx + 1.0f) * 32.0f - 0.5f;
        float fy = (gy + 1.0f) * 32.0f - 0.5f;
        float xf = floorf(fx), yf = floorf(fy);
        float wx = fx - xf,    wy = fy - yf;
        int x0 = (int)xf, y0 = (int)yf, x1 = x0 + 1, y1 = y0 + 1;
        float vx0 = (x0 >= 0 && x0 < 64) ? 1.0f : 0.0f;
        float vx1 = (x1 >= 0 && x1 < 64) ? 1.0f : 0.0f;
        float vy0 = (y0 >= 0 && y0 < 64) ? 1.0f : 0.0f;
        float vy1 = (y1 >= 0 && y1 < 64) ? 1.0f : 0.0f;
        int cx0 = min(max(x0, 0), 63), cx1 = min(max(x1, 0), 63);
        int cy0 = min(max(y0, 0), 63), cy1 = min(max(y1, 0), 63);
        float f00 = (1.0f - wx) * (1.0f - wy) * vx0 * vy0;
        float f01 = wx * (1.0f - wy) * vx1 * vy0;
        float f10 = (1.0f - wx) * wy * vx0 * vy1;
        float f11 = wx * wy * vx1 * vy1;
        uint4 wq;
        { PkU pk; _Float16 h;
          h = (_Float16)f00; pk.v = f16x2{h, h}; wq.x = pk.u;
          h = (_Float16)f01; pk.v = f16x2{h, h}; wq.y = pk.u;
          h = (_Float16)f10; pk.v = f16x2{h, h}; wq.z = pk.u;
          h = (_Float16)f11; pk.v = f16x2{h, h}; wq.w = pk.u; }
        int base = (n * 3 + p) * 4096;
        uint4 oq;
        oq.x = (unsigned)((base + (cy0 << 6) + cx0) * HID);
        oq.y = (unsigned)((base + (cy0 << 6) + cx1) * HID);
        oq.z = (unsigned)((base + (cy1 << 6) + cx0) * HID);
        oq.w = (unsigned)((base + (cy1 << 6) + cx1) * HID);
        sSet[i][p][0] = oq;
        sSet[i][p][1] = wq;
    }
    __syncthreads();   // the ONLY block-wide barrier

    // ---------- Sub-phase B: gather + layer-1 accumulate (pk_fma) ----------
    {
        int sub = lane & 7;                  // 8-dim octet
        int ptg = lane >> 3;                 // point group

        // b1 slice as 4 packed fp16 pairs.
        unsigned bp0, bp1, bp2, bp3;
        {
            const float4* bpp = (const float4*)(b1 + sub * 8);
            float4 v0 = bpp[0], v1 = bpp[1];
            PkU pk;
            pk.v = f16x2{(_Float16)v0.x, (_Float16)v0.y}; bp0 = pk.u;
            pk.v = f16x2{(_Float16)v0.z, (_Float16)v0.w}; bp1 = pk.u;
            pk.v = f16x2{(_Float16)v1.x, (_Float16)v1.y}; bp2 = pk.u;
            pk.v = f16x2{(_Float16)v1.z, (_Float16)v1.w}; bp3 = pk.u;
        }
        const unsigned short* pw = planesW + sub * 8;

        auto do_round = [&](int pt) {
            int pl = wave * 16 + pt;
            uint4 o0 = sSet[pl][0][0], w0c = sSet[pl][0][1];
            uint4 o1 = sSet[pl][1][0], w1c = sSet[pl][1][1];
            uint4 o2 = sSet[pl][2][0], w2c = sSet[pl][2][1];

            FragH u0, u1, u2, u3, u4, u5, u6, u7, u8, u9, u10, u11;
            u0.q  = *(const uint4*)(pw + o0.x);
            u1.q  = *(const uint4*)(pw + o0.y);
            u2.q  = *(const uint4*)(pw + o0.z);
            u3.q  = *(const uint4*)(pw + o0.w);
            u4.q  = *(const uint4*)(pw + o1.x);
            u5.q  = *(const uint4*)(pw + o1.y);
            u6.q  = *(const uint4*)(pw + o1.z);
            u7.q  = *(const uint4*)(pw + o1.w);
            u8.q  = *(const uint4*)(pw + o2.x);
            u9.q  = *(const uint4*)(pw + o2.y);
            u10.q = *(const uint4*)(pw + o2.z);
            u11.q = *(const uint4*)(pw + o2.w);

            unsigned a0 = bp0, a1 = bp1, a2 = bp2, a3 = bp3;

            #define TEXEL(T, WB) { pk_fma(a0, T.d[0], WB); pk_fma(a1, T.d[1], WB); \
                                   pk_fma(a2, T.d[2], WB); pk_fma(a3, T.d[3], WB); }
            TEXEL(u0,  w0c.x) TEXEL(u1,  w0c.y) TEXEL(u2,  w0c.z) TEXEL(u3,  w0c.w)
            TEXEL(u4,  w1c.x) TEXEL(u5,  w1c.y) TEXEL(u6,  w1c.z) TEXEL(u7,  w1c.w)
            TEXEL(u8,  w2c.x) TEXEL(u9,  w2c.y) TEXEL(u10, w2c.z) TEXEL(u11, w2c.w)
            #undef TEXEL

            uint4 hv;
            hv.x = pk_relu(a0); hv.y = pk_relu(a1);
            hv.z = pk_relu(a2); hv.w = pk_relu(a3);
            *(uint4*)(hwh + pt * 72 + sub * 8) = hv;
        };
        do_round(ptg);
        do_round(8 + ptg);
    }
    // No block barrier: H tile is wave-private; compiler orders LDS hazards.

    // ---------- Layer 2: K=64, A from LDS, B from LDS ----------------------
    int row  = lane & 15;
    int kgrp = lane >> 4;
    f32x4 acc2[4] = {{0,0,0,0},{0,0,0,0},{0,0,0,0},{0,0,0,0}};
    #pragma unroll
    for (int kk = 0; kk < 2; ++kk) {
        FragH au;
        au.q = *(const uint4*)(hw + row * 72 + kk * 32 + kgrp * 8);
        #pragma unroll
        for (int nt = 0; nt < 4; ++nt) {
            FragH bu;
            bu.q = *(const uint4*)(sW23 + (kk * 4 + nt) * 512 + lane * 8);
            acc2[nt] = __builtin_amdgcn_mfma_f32_16x16x32_f16(au.v, bu.v, acc2[nt], 0, 0, 0);
        }
    }

    // Epilogue 2 (biases from LDS; wave-private tile, no block barrier)
    #pragma unroll
    for (int nt = 0; nt < 4; ++nt) {
        float bb = sBias[nt * 16 + row];
        #pragma unroll
        for (int r = 0; r < 4; ++r) {
            float h = fmaxf(acc2[nt][r] + bb, 0.0f);
            hwh[(kgrp * 4 + r) * 72 + nt * 16 + row] = (_Float16)h;
        }
    }

    // ---------- Layer 3: K=64, B from LDS -----------------------------------
    f32x4 acc3[4] = {{0,0,0,0},{0,0,0,0},{0,0,0,0},{0,0,0,0}};
    #pragma unroll
    for (int kk = 0; kk < 2; ++kk) {
        FragH au;
        au.q = *(const uint4*)(hw + row * 72 + kk * 32 + kgrp * 8);
        #pragma unroll
        for (int nt = 0; nt < 4; ++nt) {
            FragH bu;
            bu.q = *(const uint4*)(sW23 + 4096 + (kk * 4 + nt) * 512 + lane * 8);
            acc3[nt] = __builtin_amdgcn_mfma_f32_16x16x32_f16(au.v, bu.v, acc3[nt], 0, 0, 0);
        }
    }

    // ---------- Layer 4: 64 -> 1, fp32 VALU + 16-lane reduce ----------------
    float part[4] = {0.f, 0.f, 0.f, 0.f};
    #pragma unroll
    for (int nt = 0; nt < 4; ++nt) {
        float bb  = sBias[64 + nt * 16 + row];
        float w4v = sBias[128 + nt * 16 + row];
        #pragma unroll
        for (int r = 0; r < 4; ++r) {
            float h = fmaxf(acc3[nt][r] + bb, 0.0f);
            part[r] += h * w4v;
        }
    }
    #pragma unroll
    for (int r = 0; r < 4; ++r) {
        #pragma unroll
        for (int off = 1; off < 16; off <<= 1)
            part[r] += __shfl_xor(part[r], off);
    }
    if (row == 0) {
        float bias4 = sBias[192];
        float4 o;
        o.x = part[0] + bias4; o.y = part[1] + bias4;
        o.z = part[2] + bias4; o.w = part[3] + bias4;
        *(float4*)(out + ptbase + kgrp * 4) = o;
    }
}

// ---------------------------------------------------------------------------
extern "C" void kernel_launch(void* const* d_in, const int* in_sizes, int n_in,
                              void* d_out, int out_size, void* d_ws, size_t ws_size,
                              hipStream_t stream) {
    const float* planes = (const float*)d_in[0];
    const float* coords = (const float*)d_in[1];
    const float* W1 = (const float*)d_in[2];
    const float* b1 = (const float*)d_in[3];
    const float* W2 = (const float*)d_in[4];
    const float* b2 = (const float*)d_in[5];
    const float* W3 = (const float*)d_in[6];
    const float* b3 = (const float*)d_in[7];
    const float* W4 = (const float*)d_in[8];
    const float* b4 = (const float*)d_in[9];
    float* out = (float*)d_out;

    // Workspace: planesW fp16 (3,145,728 B) | wpack fp16 (16,384 B)
    unsigned short* planesW = (unsigned short*)d_ws;
    unsigned short* wpack   = (unsigned short*)((char*)d_ws + 3145728);

    hipLaunchKernelGGL(precompute_planesW, dim3(NB * 3 * HWDIM), dim3(256), 0, stream,
                       planes, W1, planesW);
    hipLaunchKernelGGL(pack_weights23, dim3(32), dim3(256), 0, stream,
                       W2, W3, wpack);

    int nblocks = NPTS / 64;   // 16384
    hipLaunchKernelGGL(fused_kernel, dim3(nblocks), dim3(256), 0, stream,
                       planesW, coords, wpack, b1, b2, b3, W4, b4, out);
}

// Round 12
// 90.529 us; speedup vs baseline: 2.8896x; 1.0672x over previous
//
#include <hip/hip_runtime.h>
#include <hip/hip_bf16.h>
#include <stdint.h>

// Problem constants
#define MPTS  524288      // M per batch
#define NB    2           // N
#define CCH   80          // C
#define HWDIM 64          // H = W
#define HID   64
#define NPTS  (NB * MPTS) // 2^20

typedef _Float16 f16x2 __attribute__((ext_vector_type(2)));
typedef _Float16 f16x8 __attribute__((ext_vector_type(8)));
typedef float    f32x4 __attribute__((ext_vector_type(4)));

union FragH { uint4 q; f16x8 v; f16x2 h2[4]; unsigned d[4]; _Float16 h[8]; };
union PkU   { f16x2 v; unsigned u; };

// v_pk_fma_f16: acc.lo += a.lo*b.lo ; acc.hi += a.hi*b.hi  (1 VALU op, 2 MACs)
__device__ __forceinline__ void pk_fma(unsigned& acc, unsigned a, unsigned b) {
    asm volatile("v_pk_fma_f16 %0, %1, %2, %0" : "+v"(acc) : "v"(a), "v"(b));
}
__device__ __forceinline__ unsigned pk_relu(unsigned a) {
    unsigned r;
    asm volatile("v_pk_max_f16 %0, %1, %2" : "=v"(r) : "v"(a), "v"(0u));
    return r;
}

// ---------------------------------------------------------------------------
// Pre-kernel: planesW[np][y][x][64] fp16 = texel(80ch fp32) @ W1_p(80x64).
__global__ void precompute_planesW(const float* __restrict__ planes,
                                   const float* __restrict__ W1,
                                   unsigned short* __restrict__ planesW) {
    __shared__ float tA[CCH * 64];   // [c][px]
    __shared__ float tW[CCH * 64];   // [c][nn]
    int b  = blockIdx.x;
    int np = b >> 6, y = b & 63;
    int p  = np % 3;
    int t  = threadIdx.x;
    for (int i = t; i < CCH * 64; i += 256) {
        int c = i >> 6, x = i & 63;
        tA[i] = planes[((size_t)np * CCH + c) * 4096 + y * 64 + x];
        tW[i] = W1[(p * CCH + c) * HID + x];
    }
    __syncthreads();
    int px = t >> 2;
    int n0 = (t & 3) * 16;
    float acc[16];
    #pragma unroll
    for (int i = 0; i < 16; ++i) acc[i] = 0.0f;
    for (int c = 0; c < CCH; ++c) {
        float a = tA[c * 64 + px];
        #pragma unroll
        for (int i = 0; i < 16; ++i) acc[i] += a * tW[c * 64 + n0 + i];
    }
    unsigned short* dst = planesW + (((size_t)np * 4096) + y * 64 + px) * HID + n0;
    #pragma unroll
    for (int i = 0; i < 16; ++i) {
        union { _Float16 h; unsigned short u; } cv;
        cv.h = (_Float16)acc[i];
        dst[i] = cv.u;
    }
}

// ---------------------------------------------------------------------------
// Pre-kernel: W2, W3 (64x64) fp16 MFMA B-fragment order (proven layout).
__global__ void pack_weights23(const float* __restrict__ W2,
                               const float* __restrict__ W3,
                               unsigned short* __restrict__ wpack) {
    int e = blockIdx.x * 256 + threadIdx.x;   // 0..8191
    const float* W = (e < 4096) ? W2 : W3;
    int q  = e & 4095;
    int j  = q & 7;
    int l  = (q >> 3) & 63;
    int nt = (q >> 9) & 3;
    int kb = q >> 11;
    int k  = kb * 32 + ((l >> 4) << 3) + j;
    int nn = nt * 16 + (l & 15);
    union { _Float16 h; unsigned short u; } cv;
    cv.h = (_Float16)W[k * HID + nn];
    wpack[e] = cv.u;
}

// ---------------------------------------------------------------------------
// Main fused kernel: 512 threads = 8 waves, 128 points per block.
// LDS ~48 KB -> 3 blocks/CU = 24 waves/CU (75%) for latency hiding;
// sW23 staging amortized over 2x points.
__global__ __launch_bounds__(512, 6) void fused_kernel(
        const unsigned short* __restrict__ planesW,
        const float* __restrict__ coords,
        const unsigned short* __restrict__ wpack,
        const float* __restrict__ b1, const float* __restrict__ b2,
        const float* __restrict__ b3, const float* __restrict__ W4,
        const float* __restrict__ b4, float* __restrict__ out) {

    __shared__ __align__(16) unsigned short sH[8 * 16 * 72]; // per-wave H tiles (18.4 KB)
    __shared__ __align__(16) uint4 sSet[128][3][2];          // {off4, wpk4} per (pt, plane) (12.3 KB)
    __shared__ __align__(16) unsigned short sW23[8192];      // W2|W3 fragments (16 KB = 1024 uint4)
    __shared__ float sBias[196];                             // b2[0:64) b3[64:128) W4[128:192) b4[192]

    int t    = threadIdx.x;
    int wave = t >> 6, lane = t & 63;
    int ptbase = blockIdx.x * 128 + wave * 16;

    unsigned short* hw = sH + wave * (16 * 72);
    _Float16* hwh = (_Float16*)hw;

    // ---------- Stage W2/W3 fragments + biases into LDS --------------------
    {
        const uint4* g = (const uint4*)wpack;
        uint4* s = (uint4*)sW23;
        s[t]       = g[t];          // 1024 uint4 over 512 threads = 2 chunks
        s[t + 512] = g[t + 512];
        if (t < 64)        sBias[t] = b2[t];
        else if (t < 128)  sBias[t] = b3[t - 64];
        else if (t < 192)  sBias[t] = W4[t - 128];
        else if (t == 192) sBias[192] = b4[0];
    }

    // ---------- Sub-phase A: per-point bilinear setup, deduplicated --------
    // 384 threads cover 128 points x 3 planes.
    if (t < 384) {
        int i  = t & 127;                    // local point
        int p  = t >> 7;                     // plane (wave-pair-uniform)
        int mypt = blockIdx.x * 128 + i;
        int n    = mypt >> 19;               // MPTS = 2^19
        const float* cp = coords + (size_t)mypt * 3;
        float c0 = cp[0], c1 = cp[1], c2 = cp[2];
        float gx = (p == 2) ? c2 : c0;       // p0:(x,y) p1:(x,z) p2:(z,y)
        float gy = (p == 1) ? c2 : c1;
        float fx = (gx + 1.0f) * 32.0f - 0.5f;
        float fy = (gy + 1.0f) * 32.0f - 0.5f;
        float xf = floorf(fx), yf = floorf(fy);
        float wx = fx - xf,    wy = fy - yf;
        int x0 = (int)xf, y0 = (int)yf, x1 = x0 + 1, y1 = y0 + 1;
        float vx0 = (x0 >= 0 && x0 < 64) ? 1.0f : 0.0f;
        float vx1 = (x1 >= 0 && x1 < 64) ? 1.0f : 0.0f;
        float vy0 = (y0 >= 0 && y0 < 64) ? 1.0f : 0.0f;
        float vy1 = (y1 >= 0 && y1 < 64) ? 1.0f : 0.0f;
        int cx0 = min(max(x0, 0), 63), cx1 = min(max(x1, 0), 63);
        int cy0 = min(max(y0, 0), 63), cy1 = min(max(y1, 0), 63);
        float f00 = (1.0f - wx) * (1.0f - wy) * vx0 * vy0;
        float f01 = wx * (1.0f - wy) * vx1 * vy0;
        float f10 = (1.0f - wx) * wy * vx0 * vy1;
        float f11 = wx * wy * vx1 * vy1;
        uint4 wq;
        { PkU pk; _Float16 h;
          h = (_Float16)f00; pk.v = f16x2{h, h}; wq.x = pk.u;
          h = (_Float16)f01; pk.v = f16x2{h, h}; wq.y = pk.u;
          h = (_Float16)f10; pk.v = f16x2{h, h}; wq.z = pk.u;
          h = (_Float16)f11; pk.v = f16x2{h, h}; wq.w = pk.u; }
        int base = (n * 3 + p) * 4096;
        uint4 oq;
        oq.x = (unsigned)((base + (cy0 << 6) + cx0) * HID);
        oq.y = (unsigned)((base + (cy0 << 6) + cx1) * HID);
        oq.z = (unsigned)((base + (cy1 << 6) + cx0) * HID);
        oq.w = (unsigned)((base + (cy1 << 6) + cx1) * HID);
        sSet[i][p][0] = oq;
        sSet[i][p][1] = wq;
    }
    __syncthreads();   // the ONLY block-wide barrier

    // ---------- Sub-phase B: gather + layer-1 accumulate (pk_fma) ----------
    {
        int sub = lane & 7;                  // 8-dim octet
        int ptg = lane >> 3;                 // point group

        unsigned bp0, bp1, bp2, bp3;
        {
            const float4* bpp = (const float4*)(b1 + sub * 8);
            float4 v0 = bpp[0], v1 = bpp[1];
            PkU pk;
            pk.v = f16x2{(_Float16)v0.x, (_Float16)v0.y}; bp0 = pk.u;
            pk.v = f16x2{(_Float16)v0.z, (_Float16)v0.w}; bp1 = pk.u;
            pk.v = f16x2{(_Float16)v1.x, (_Float16)v1.y}; bp2 = pk.u;
            pk.v = f16x2{(_Float16)v1.z, (_Float16)v1.w}; bp3 = pk.u;
        }
        const unsigned short* pw = planesW + sub * 8;

        auto do_round = [&](int pt) {
            int pl = wave * 16 + pt;
            uint4 o0 = sSet[pl][0][0], w0c = sSet[pl][0][1];
            uint4 o1 = sSet[pl][1][0], w1c = sSet[pl][1][1];
            uint4 o2 = sSet[pl][2][0], w2c = sSet[pl][2][1];

            FragH u0, u1, u2, u3, u4, u5, u6, u7, u8, u9, u10, u11;
            u0.q  = *(const uint4*)(pw + o0.x);
            u1.q  = *(const uint4*)(pw + o0.y);
            u2.q  = *(const uint4*)(pw + o0.z);
            u3.q  = *(const uint4*)(pw + o0.w);
            u4.q  = *(const uint4*)(pw + o1.x);
            u5.q  = *(const uint4*)(pw + o1.y);
            u6.q  = *(const uint4*)(pw + o1.z);
            u7.q  = *(const uint4*)(pw + o1.w);
            u8.q  = *(const uint4*)(pw + o2.x);
            u9.q  = *(const uint4*)(pw + o2.y);
            u10.q = *(const uint4*)(pw + o2.z);
            u11.q = *(const uint4*)(pw + o2.w);

            unsigned a0 = bp0, a1 = bp1, a2 = bp2, a3 = bp3;

            #define TEXEL(T, WB) { pk_fma(a0, T.d[0], WB); pk_fma(a1, T.d[1], WB); \
                                   pk_fma(a2, T.d[2], WB); pk_fma(a3, T.d[3], WB); }
            TEXEL(u0,  w0c.x) TEXEL(u1,  w0c.y) TEXEL(u2,  w0c.z) TEXEL(u3,  w0c.w)
            TEXEL(u4,  w1c.x) TEXEL(u5,  w1c.y) TEXEL(u6,  w1c.z) TEXEL(u7,  w1c.w)
            TEXEL(u8,  w2c.x) TEXEL(u9,  w2c.y) TEXEL(u10, w2c.z) TEXEL(u11, w2c.w)
            #undef TEXEL

            uint4 hv;
            hv.x = pk_relu(a0); hv.y = pk_relu(a1);
            hv.z = pk_relu(a2); hv.w = pk_relu(a3);
            *(uint4*)(hwh + pt * 72 + sub * 8) = hv;
        };
        do_round(ptg);
        do_round(8 + ptg);
    }
    // No block barrier: H tile is wave-private; compiler orders LDS hazards.

    // ---------- Layer 2: K=64, A from LDS, B from LDS ----------------------
    int row  = lane & 15;
    int kgrp = lane >> 4;
    f32x4 acc2[4] = {{0,0,0,0},{0,0,0,0},{0,0,0,0},{0,0,0,0}};
    #pragma unroll
    for (int kk = 0; kk < 2; ++kk) {
        FragH au;
        au.q = *(const uint4*)(hw + row * 72 + kk * 32 + kgrp * 8);
        #pragma unroll
        for (int nt = 0; nt < 4; ++nt) {
            FragH bu;
            bu.q = *(const uint4*)(sW23 + (kk * 4 + nt) * 512 + lane * 8);
            acc2[nt] = __builtin_amdgcn_mfma_f32_16x16x32_f16(au.v, bu.v, acc2[nt], 0, 0, 0);
        }
    }

    // Epilogue 2 (biases from LDS; wave-private tile, no block barrier)
    #pragma unroll
    for (int nt = 0; nt < 4; ++nt) {
        float bb = sBias[nt * 16 + row];
        #pragma unroll
        for (int r = 0; r < 4; ++r) {
            float h = fmaxf(acc2[nt][r] + bb, 0.0f);
            hwh[(kgrp * 4 + r) * 72 + nt * 16 + row] = (_Float16)h;
        }
    }

    // ---------- Layer 3: K=64, B from LDS -----------------------------------
    f32x4 acc3[4] = {{0,0,0,0},{0,0,0,0},{0,0,0,0},{0,0,0,0}};
    #pragma unroll
    for (int kk = 0; kk < 2; ++kk) {
        FragH au;
        au.q = *(const uint4*)(hw + row * 72 + kk * 32 + kgrp * 8);
        #pragma unroll
        for (int nt = 0; nt < 4; ++nt) {
            FragH bu;
            bu.q = *(const uint4*)(sW23 + 4096 + (kk * 4 + nt) * 512 + lane * 8);
            acc3[nt] = __builtin_amdgcn_mfma_f32_16x16x32_f16(au.v, bu.v, acc3[nt], 0, 0, 0);
        }
    }

    // ---------- Layer 4: 64 -> 1, fp32 VALU + 16-lane reduce ----------------
    float part[4] = {0.f, 0.f, 0.f, 0.f};
    #pragma unroll
    for (int nt = 0; nt < 4; ++nt) {
        float bb  = sBias[64 + nt * 16 + row];
        float w4v = sBias[128 + nt * 16 + row];
        #pragma unroll
        for (int r = 0; r < 4; ++r) {
            float h = fmaxf(acc3[nt][r] + bb, 0.0f);
            part[r] += h * w4v;
        }
    }
    #pragma unroll
    for (int r = 0; r < 4; ++r) {
        #pragma unroll
        for (int off = 1; off < 16; off <<= 1)
            part[r] += __shfl_xor(part[r], off);
    }
    if (row == 0) {
        float bias4 = sBias[192];
        float4 o;
        o.x = part[0] + bias4; o.y = part[1] + bias4;
        o.z = part[2] + bias4; o.w = part[3] + bias4;
        *(float4*)(out + ptbase + kgrp * 4) = o;
    }
}

// ---------------------------------------------------------------------------
extern "C" void kernel_launch(void* const* d_in, const int* in_sizes, int n_in,
                              void* d_out, int out_size, void* d_ws, size_t ws_size,
                              hipStream_t stream) {
    const float* planes = (const float*)d_in[0];
    const float* coords = (const float*)d_in[1];
    const float* W1 = (const float*)d_in[2];
    const float* b1 = (const float*)d_in[3];
    const float* W2 = (const float*)d_in[4];
    const float* b2 = (const float*)d_in[5];
    const float* W3 = (const float*)d_in[6];
    const float* b3 = (const float*)d_in[7];
    const float* W4 = (const float*)d_in[8];
    const float* b4 = (const float*)d_in[9];
    float* out = (float*)d_out;

    // Workspace: planesW fp16 (3,145,728 B) | wpack fp16 (16,384 B)
    unsigned short* planesW = (unsigned short*)d_ws;
    unsigned short* wpack   = (unsigned short*)((char*)d_ws + 3145728);

    hipLaunchKernelGGL(precompute_planesW, dim3(NB * 3 * HWDIM), dim3(256), 0, stream,
                       planes, W1, planesW);
    hipLaunchKernelGGL(pack_weights23, dim3(32), dim3(256), 0, stream,
                       W2, W3, wpack);

    int nblocks = NPTS / 128;   // 8192
    hipLaunchKernelGGL(fused_kernel, dim3(nblocks), dim3(512), 0, stream,
                       planesW, coords, wpack, b1, b2, b3, W4, b4, out);
}